// Round 3
// baseline (53.258 us; speedup 1.0000x reference)
//
#include <hip/hip_runtime.h>
#include <hip/hip_bf16.h>

#define HH 4
#define INF 256
#define OUTF 128
#define NEG_SLOPE 0.2f
#define LIST_CAP 8192

// Fused: blocks 0..7 compute u[c][i] = sum_o W[h,i,o]*a[h, kind*128+o]
// (c = kind*4 + h); remaining blocks scan edges for self-loops.
__global__ void k_prep(const float* __restrict__ W, const float* __restrict__ a,
                       const int* __restrict__ src, const int* __restrict__ dst, int E,
                       float* __restrict__ u, int* __restrict__ flag,
                       int* __restrict__ count, int* __restrict__ list) {
    if (blockIdx.x < 8) {
        int c = blockIdx.x, kind = c >> 2, h = c & 3;
        __shared__ float av[OUTF];
        int t = threadIdx.x;
        if (t < OUTF) av[t] = a[h * 2 * OUTF + kind * OUTF + t];
        __syncthreads();
        const float* Wr = W + ((size_t)(h * INF + t)) * OUTF;
        float acc = 0.f;
        #pragma unroll 8
        for (int o = 0; o < OUTF; ++o) acc += Wr[o] * av[o];
        u[c * INF + t] = acc;
    } else {
        int e = (blockIdx.x - 8) * blockDim.x + threadIdx.x;
        if (e < E) {
            int s = src[e], d = dst[e];
            if (s == d) {
                flag[s] = 1;
                int pos = atomicAdd(count, 1);
                if (pos < LIST_CAP) list[pos] = e;
            }
        }
    }
}

// s_src[n].h = x[n,:]·u[0*4+h], s_dst[n].h = x[n,:]·u[1*4+h]
// one wave (64 lanes) per node; lane loads float4 (16B).
__global__ void k_s(const float* __restrict__ x, const float* __restrict__ u,
                    float4* __restrict__ s_src, float4* __restrict__ s_dst, int N) {
    __shared__ float uL[8][INF];
    for (int i = threadIdx.x; i < 8 * INF; i += blockDim.x)
        uL[i >> 8][i & 255] = u[i];
    __syncthreads();
    int wave = threadIdx.x >> 6, lane = threadIdx.x & 63;
    int n = blockIdx.x * 4 + wave;
    if (n >= N) return;
    float4 xv4 = *(const float4*)(x + (size_t)n * INF + lane * 4);
    float xv[4] = {xv4.x, xv4.y, xv4.z, xv4.w};
    float p[8];
    #pragma unroll
    for (int c = 0; c < 8; ++c) {
        float acc = 0.f;
        #pragma unroll
        for (int j = 0; j < 4; ++j) acc += xv[j] * uL[c][lane * 4 + j];
        p[c] = acc;
    }
    #pragma unroll
    for (int c = 0; c < 8; ++c)
        #pragma unroll
        for (int off = 32; off; off >>= 1) p[c] += __shfl_down(p[c], off, 64);
    if (lane == 0) {
        s_src[n] = make_float4(p[0], p[1], p[2], p[3]);
        s_dst[n] = make_float4(p[4], p[5], p[6], p[7]);
    }
}

// denom[n*4+h] = sum over edges with dst==n of exp(lrelu(s)) — only for
// flagged (self-loop) nodes; wsum collects the self-edge contributions.
// No max-shift: logits bounded (~±16), expf fits fp32; cancels in wsum/denom.
__global__ void k_denom(const int* __restrict__ src, const int* __restrict__ dst, int E,
                        const int* __restrict__ flag,
                        const float4* __restrict__ s_src, const float4* __restrict__ s_dst,
                        float* __restrict__ denom, float* __restrict__ wsum) {
    int e = blockIdx.x * blockDim.x + threadIdx.x;
    if (e >= E) return;
    int d = dst[e];
    if (!flag[d]) return;
    int s = src[e];
    float4 sa = s_src[s], sb = s_dst[d];
    float eh[4] = {sa.x + sb.x, sa.y + sb.y, sa.z + sb.z, sa.w + sb.w};
    bool selfe = (s == d);
    #pragma unroll
    for (int h = 0; h < 4; ++h) {
        float z = eh[h];
        z = z > 0.f ? z : NEG_SLOPE * z;
        float w = expf(z);
        atomicAdd(&denom[d * 4 + h], w);
        if (selfe) atomicAdd(&wsum[d * 4 + h], w);
    }
}

// For each self-loop edge: n = src[e]; out[n, h*128+o] = diag[h,n] * x_t[h,n,o]
// with x_t computed on the fly (x[n,:] @ W[h]). Duplicate self-edges write
// identical rows (diag already aggregated) — benign.
__global__ void k_out(const float* __restrict__ x, const float* __restrict__ W,
                      const int* __restrict__ src,
                      const int* __restrict__ count, const int* __restrict__ list,
                      const float* __restrict__ denom, const float* __restrict__ wsum,
                      float* __restrict__ out) {
    int cnt = *count;
    if (cnt > LIST_CAP) cnt = LIST_CAP;
    __shared__ float xL[INF];
    for (int idx = blockIdx.x; idx < cnt; idx += gridDim.x) {
        int e = list[idx];
        int n = src[e];
        __syncthreads();
        for (int t = threadIdx.x; t < INF; t += blockDim.x)
            xL[t] = x[(size_t)n * INF + t];
        __syncthreads();
        int t = threadIdx.x;            // 512 threads: h = t>>7, o = t&127
        int h = t >> 7, o = t & 127;
        float dg = wsum[n * 4 + h] / (denom[n * 4 + h] + 1e-16f);
        const float* Wc = W + (size_t)h * INF * OUTF + o;
        float acc = 0.f;
        #pragma unroll 8
        for (int i = 0; i < INF; ++i) acc += xL[i] * Wc[(size_t)i * OUTF];
        out[(size_t)n * (HH * OUTF) + h * OUTF + o] = dg * acc;
    }
}

extern "C" void kernel_launch(void* const* d_in, const int* in_sizes, int n_in,
                              void* d_out, int out_size, void* d_ws, size_t ws_size,
                              hipStream_t stream) {
    const float* x = (const float*)d_in[0];
    const float* W = (const float*)d_in[1];
    const float* a = (const float*)d_in[2];
    const int* ei = (const int*)d_in[3];
    int N = in_sizes[0] / INF;     // 15000
    int E = in_sizes[3] / 2;       // 720000
    const int* src = ei;
    const int* dst = ei + E;

    char* ws = (char*)d_ws;
    float*  u     = (float*)ws;                                  // 8KB
    float4* ssrc  = (float4*)(ws + 8192);                        // 16N
    float4* sdst  = (float4*)(ws + 8192 + (size_t)N * 16);       // 16N
    size_t zoff   = 8192 + (size_t)N * 32;
    float*  denom = (float*)(ws + zoff);                         // 16N
    float*  wsum  = (float*)(ws + zoff + (size_t)N * 16);        // 16N
    int*    flag  = (int*)  (ws + zoff + (size_t)N * 32);        // 4N
    int*    count = (int*)  (ws + zoff + (size_t)N * 36);        // 4
    int*    list  = count + 1;                                   // LIST_CAP*4
    size_t zbytes = (size_t)N * 36 + 4;

    hipMemsetAsync(ws + zoff, 0, zbytes, stream);
    hipMemsetAsync(d_out, 0, (size_t)out_size * sizeof(float), stream);

    int eblocks = (E + 255) / 256;
    k_prep<<<8 + eblocks, 256, 0, stream>>>(W, a, src, dst, E, u, flag, count, list);
    k_s<<<(N + 3) / 4, 256, 0, stream>>>(x, u, ssrc, sdst, N);
    k_denom<<<eblocks, 256, 0, stream>>>(src, dst, E, flag, ssrc, sdst, denom, wsum);
    k_out<<<128, 512, 0, stream>>>(x, W, src, count, list, denom, wsum, (float*)d_out);
}